// Round 2
// baseline (194.494 us; speedup 1.0000x reference)
//
#include <hip/hip_runtime.h>
#include <math.h>

#define FEAT 4096
#define BATCH 4096

// One block per row. All 12 float4 loads issued before any use -> high MLP.
// Block computes relu(2 - ||o1-o3|| + ||o1-o2||) * BATCH and atomically adds
// to the scalar output (broadcast-sum semantics of the reference).
__global__ __launch_bounds__(256) void fused_loss_kernel(
    const float* __restrict__ o1, const float* __restrict__ o2,
    const float* __restrict__ o3, float* __restrict__ out)
{
    const int row = blockIdx.x;
    const int tid = threadIdx.x;
    const float4* p1 = (const float4*)(o1 + (size_t)row * FEAT);
    const float4* p2 = (const float4*)(o2 + (size_t)row * FEAT);
    const float4* p3 = (const float4*)(o3 + (size_t)row * FEAT);

    // Issue all 12 independent loads up front (16 B/lane, coalesced).
    const float4 a0 = p1[tid];
    const float4 a1 = p1[tid + 256];
    const float4 a2 = p1[tid + 512];
    const float4 a3 = p1[tid + 768];
    const float4 c0 = p3[tid];
    const float4 c1 = p3[tid + 256];
    const float4 c2 = p3[tid + 512];
    const float4 c3 = p3[tid + 768];
    const float4 b0 = p2[tid];
    const float4 b1 = p2[tid + 256];
    const float4 b2 = p2[tid + 512];
    const float4 b3 = p2[tid + 768];

    float s13 = 0.0f, s12 = 0.0f;
    float d;
    // s13 uses a,c (ready first); s12 uses a,b (ready last).
    d = a0.x - c0.x; s13 += d * d;  d = a0.y - c0.y; s13 += d * d;
    d = a0.z - c0.z; s13 += d * d;  d = a0.w - c0.w; s13 += d * d;
    d = a1.x - c1.x; s13 += d * d;  d = a1.y - c1.y; s13 += d * d;
    d = a1.z - c1.z; s13 += d * d;  d = a1.w - c1.w; s13 += d * d;
    d = a2.x - c2.x; s13 += d * d;  d = a2.y - c2.y; s13 += d * d;
    d = a2.z - c2.z; s13 += d * d;  d = a2.w - c2.w; s13 += d * d;
    d = a3.x - c3.x; s13 += d * d;  d = a3.y - c3.y; s13 += d * d;
    d = a3.z - c3.z; s13 += d * d;  d = a3.w - c3.w; s13 += d * d;

    d = a0.x - b0.x; s12 += d * d;  d = a0.y - b0.y; s12 += d * d;
    d = a0.z - b0.z; s12 += d * d;  d = a0.w - b0.w; s12 += d * d;
    d = a1.x - b1.x; s12 += d * d;  d = a1.y - b1.y; s12 += d * d;
    d = a1.z - b1.z; s12 += d * d;  d = a1.w - b1.w; s12 += d * d;
    d = a2.x - b2.x; s12 += d * d;  d = a2.y - b2.y; s12 += d * d;
    d = a2.z - b2.z; s12 += d * d;  d = a2.w - b2.w; s12 += d * d;
    d = a3.x - b3.x; s12 += d * d;  d = a3.y - b3.y; s12 += d * d;
    d = a3.z - b3.z; s12 += d * d;  d = a3.w - b3.w; s12 += d * d;

    // wave(64)-level butterfly reduce
    #pragma unroll
    for (int off = 32; off > 0; off >>= 1) {
        s13 += __shfl_down(s13, off, 64);
        s12 += __shfl_down(s12, off, 64);
    }

    __shared__ float ls13[4];
    __shared__ float ls12[4];
    const int wave = tid >> 6;
    const int lane = tid & 63;
    if (lane == 0) { ls13[wave] = s13; ls12[wave] = s12; }
    __syncthreads();
    if (tid == 0) {
        const float t13 = ls13[0] + ls13[1] + ls13[2] + ls13[3];
        const float t12 = ls12[0] + ls12[1] + ls12[2] + ls12[3];
        const float compare = 2.0f - sqrtf(t13) + sqrtf(t12);
        const float v = fmaxf(compare, 0.0f) * (float)BATCH;
        atomicAdd(out, v);   // 4096 adds to one address; device-scope by default
    }
}

extern "C" void kernel_launch(void* const* d_in, const int* in_sizes, int n_in,
                              void* d_out, int out_size, void* d_ws, size_t ws_size,
                              hipStream_t stream) {
    const float* o1 = (const float*)d_in[0];
    const float* o2 = (const float*)d_in[1];
    const float* o3 = (const float*)d_in[2];
    float* out = (float*)d_out;  // single fp32 scalar

    hipMemsetAsync(out, 0, sizeof(float) * out_size, stream);
    fused_loss_kernel<<<BATCH, 256, 0, stream>>>(o1, o2, o3, out);
}